// Round 4
// baseline (5449.474 us; speedup 1.0000x reference)
//
#include <hip/hip_runtime.h>
#include <hip/hip_bf16.h>

typedef unsigned short u16;
typedef unsigned int u32;
typedef __attribute__((ext_vector_type(8))) short short8;
typedef __attribute__((ext_vector_type(4))) float f32x4;

__device__ __forceinline__ u32 bf16_rne(float f) {
    u32 u = __float_as_uint(f);
    return (u + 0x7FFFu + ((u >> 16) & 1u)) >> 16;
}

// column permutation: orig col c = k*4096 + g*1024 + hx  ->  n = hx*16 + k*4 + g
__device__ __forceinline__ int permcol(int c) {
    return (c & 1023) * 16 + ((c >> 12) & 3) * 4 + ((c >> 10) & 3);
}

__device__ __forceinline__ float sigf(float x) { return 1.0f / (1.0f + expf(-x)); }

// Fragment-swizzled layout for an [R][1024] matrix (R rows, K contiguous frags):
// elem(r,k) -> (((r>>4)*128 + (k>>3)) * 128) + (r&15)*8 + (k&7)
// A wave's 16x16x32-MFMA frag load (16 rows x 8 k per quad) is then 1 KB contiguous.
__device__ __forceinline__ size_t sidx(int r, int k) {
    return (((size_t)(r >> 4) * 128 + (k >> 3)) << 7) + ((r & 15) << 3) + (k & 7);
}

// ---------------------------------------------------------------------------
// Transpose + split fp32 [1024][N] -> bf16 hi/lo, frag-swizzled [N'][1024]
// ---------------------------------------------------------------------------
template <bool PERM>
__global__ __launch_bounds__(256) void transpose_split(
    const float* __restrict__ W, u16* __restrict__ Thi, u16* __restrict__ Tlo, int N)
{
    __shared__ float tile[64][65];
    int n0 = blockIdx.x * 64;
    int k0 = blockIdx.y * 64;
    int tid = threadIdx.x;
    int tr = tid >> 4;      // 0..15
    int tc = tid & 15;      // 0..15
#pragma unroll
    for (int it = 0; it < 4; ++it) {
        int kr = it * 16 + tr;
        const float4* src = (const float4*)&W[(size_t)(k0 + kr) * N + n0 + tc * 4];
        float4 v = *src;
        tile[kr][tc * 4 + 0] = v.x;
        tile[kr][tc * 4 + 1] = v.y;
        tile[kr][tc * 4 + 2] = v.z;
        tile[kr][tc * 4 + 3] = v.w;
    }
    __syncthreads();
#pragma unroll
    for (int it = 0; it < 4; ++it) {
        int nr = it * 16 + tr;
        u32 h[4], l[4];
#pragma unroll
        for (int j = 0; j < 4; ++j) {
            float f = tile[tc * 4 + j][nr];
            u32 hi = bf16_rne(f);
            float hif = __uint_as_float(hi << 16);
            float lo = f - hif;
            h[j] = hi;
            l[j] = bf16_rne(lo);
        }
        int ng = n0 + nr;
        int pr = PERM ? permcol(ng) : ng;
        int kk = k0 + tc * 4;                 // 4 consecutive k within one k-block
        size_t idx = sidx(pr, kk);
        uint2 ph, pl;
        ph.x = h[0] | (h[1] << 16); ph.y = h[2] | (h[3] << 16);
        pl.x = l[0] | (l[1] << 16); pl.y = l[2] | (l[3] << 16);
        *(uint2*)&Thi[idx] = ph;
        *(uint2*)&Tlo[idx] = pl;
    }
}

// ---------------------------------------------------------------------------
// Permute Wi columns: WiP[r][n] = Wi[r][orig(n)]
// ---------------------------------------------------------------------------
__global__ __launch_bounds__(256) void permute_wi(
    const float* __restrict__ Wi, float* __restrict__ WiP)
{
    __shared__ float l[256 * 17];
    int r = blockIdx.y, hb = blockIdx.x, tid = threadIdx.x;
    const float* src = Wi + (size_t)r * 16384;
    float* dst = WiP + (size_t)r * 16384;
#pragma unroll
    for (int kg = 0; kg < 16; ++kg) {
        int k = kg >> 2, g = kg & 3;
        l[tid * 17 + kg] = src[k * 4096 + g * 1024 + hb * 256 + tid];
    }
    __syncthreads();
#pragma unroll
    for (int it = 0; it < 16; ++it) {
        int j = it * 256 + tid;
        dst[hb * 4096 + j] = l[(j >> 4) * 17 + (j & 15)];
    }
}

// ---------------------------------------------------------------------------
// Init: bsum = bi + bh (plain and permuted)
// ---------------------------------------------------------------------------
__global__ __launch_bounds__(256) void init_state(
    float* __restrict__ bsum, float* __restrict__ bsumP,
    const float* __restrict__ bi, const float* __restrict__ bh)
{
    int i = blockIdx.x * 256 + threadIdx.x;   // 0..16383
    float v = bi[i] + bh[i];
    bsum[i] = v;
    bsumP[permcol(i)] = v;
}

// ---------------------------------------------------------------------------
// Step 0: h == 0, c == 0 -> gates = bsum + Wi[X[b,0]], cell update inline.
// Writes h split (swizzled layout). Thread handles (b, hx pair).
// ---------------------------------------------------------------------------
__global__ __launch_bounds__(256) void cell0(
    const float* __restrict__ bsum, const int* __restrict__ X,
    const float* __restrict__ Wi,
    float* __restrict__ c4, u16* __restrict__ Ohi, u16* __restrict__ Olo)
{
    int gid = blockIdx.x * 256 + threadIdx.x;   // 0..131071
    int b = gid >> 9;
    int hp = (gid & 511) * 2;                   // even hx
    int xr = X[b * 128];
    const float* wr = Wi + (size_t)xr * 16384;
    u32 hvh[2], hvl[2];
#pragma unroll
    for (int u = 0; u < 2; ++u) {
        int hx = hp + u;
        float best = -3.4e38f, csel = 0.0f;
        float cn[4];
#pragma unroll
        for (int k = 0; k < 4; ++k) {
            int base = k * 4096 + hx;
            float gi = bsum[base + 0]    + wr[base + 0];
            float gf = bsum[base + 1024] + wr[base + 1024];
            float gg = bsum[base + 2048] + wr[base + 2048];
            float go = bsum[base + 3072] + wr[base + 3072];
            float ig = sigf(gi);
            float fg = sigf(gf); (void)fg;       // c_old = 0
            float tg = tanhf(gg);
            cn[k] = ig * tg;
            if (go > best) { best = go; csel = cn[k]; }
        }
        float4 cv = {cn[0], cn[1], cn[2], cn[3]};
        *(float4*)&c4[((size_t)b * 1024 + hx) * 4] = cv;
        float h = sigf(best) * tanhf(csel);
        u32 hi = bf16_rne(h);
        float hif = __uint_as_float(hi << 16);
        hvh[u] = hi;
        hvl[u] = bf16_rne(h - hif);
    }
    size_t hidx = sidx(b, hp);                   // hp even -> u32-aligned, same k-block
    *(u32*)&Ohi[hidx] = hvh[0] | (hvh[1] << 16);
    *(u32*)&Olo[hidx] = hvl[0] | (hvl[1] << 16);
}

// ---------------------------------------------------------------------------
// Fused step, barrier-free K-loop: gates GEMM (bf16x3) + cell update.
// Block = 128x64 tile, 4 independent waves of 64x32 (4x2 acc).
// A (h) and B (WhT) are frag-swizzled; each frag load = coalesced dwordx4.
// No LDS staging, no __syncthreads: compiler pipelines loads with vmcnt(N).
// Epilogue per-wave: acc -> wave-private LDS tile -> cell math -> c4 + h out.
// ---------------------------------------------------------------------------
__global__ __launch_bounds__(256, 2) void fused_step(
    const u16* __restrict__ Ahi, const u16* __restrict__ Alo,
    const u16* __restrict__ Bhi, const u16* __restrict__ Blo,
    const float* __restrict__ bsumP, const float* __restrict__ WiP,
    const int* __restrict__ X, int t,
    float* __restrict__ c4, u16* __restrict__ Ohi, u16* __restrict__ Olo)
{
    __shared__ float tile[4][64 * 34];   // per-wave 64x32 (+2 pad) = 34.8 KB total

    int bid = blockIdx.x;
    int xcd = bid & 7, rr = bid >> 3;
    int m0 = (rr & 1) * 128;
    int n0 = ((rr >> 1) * 8 + xcd) * 64;
    int tid  = threadIdx.x;
    int lane = tid & 63;
    int wave = tid >> 6;
    int wm = wave >> 1, wn = wave & 1;
    int quad = lane >> 4, l15 = lane & 15;

    int mbase = (m0 + wm * 64) >> 4;     // A row-block base
    int nbase = (n0 + wn * 32) >> 4;     // B row-block base (B^T rows = cols)

    size_t aoff[4], boff[2];
#pragma unroll
    for (int mi = 0; mi < 4; ++mi)
        aoff[mi] = (((size_t)(mbase + mi) * 128 + quad) << 7) + (l15 << 3);
#pragma unroll
    for (int ni = 0; ni < 2; ++ni)
        boff[ni] = (((size_t)(nbase + ni) * 128 + quad) << 7) + (l15 << 3);

    f32x4 acc[4][2] = {};

#pragma unroll 2
    for (int kc = 0; kc < 32; ++kc) {
        int ko = kc * 512;               // 4 k-blocks * 128 elems
        short8 afh[4], afl[4], bfh[2], bfl[2];
#pragma unroll
        for (int mi = 0; mi < 4; ++mi) {
            afh[mi] = *(const short8*)(Ahi + aoff[mi] + ko);
            afl[mi] = *(const short8*)(Alo + aoff[mi] + ko);
        }
#pragma unroll
        for (int ni = 0; ni < 2; ++ni) {
            bfh[ni] = *(const short8*)(Bhi + boff[ni] + ko);
            bfl[ni] = *(const short8*)(Blo + boff[ni] + ko);
        }
        // term-major bursts: 8 independent MFMAs each; per-acc order hh, hl, lh
#pragma unroll
        for (int mi = 0; mi < 4; ++mi)
#pragma unroll
            for (int ni = 0; ni < 2; ++ni)
                acc[mi][ni] = __builtin_amdgcn_mfma_f32_16x16x32_bf16(afh[mi], bfh[ni], acc[mi][ni], 0, 0, 0);
#pragma unroll
        for (int mi = 0; mi < 4; ++mi)
#pragma unroll
            for (int ni = 0; ni < 2; ++ni)
                acc[mi][ni] = __builtin_amdgcn_mfma_f32_16x16x32_bf16(afh[mi], bfl[ni], acc[mi][ni], 0, 0, 0);
#pragma unroll
        for (int mi = 0; mi < 4; ++mi)
#pragma unroll
            for (int ni = 0; ni < 2; ++ni)
                acc[mi][ni] = __builtin_amdgcn_mfma_f32_16x16x32_bf16(afl[mi], bfh[ni], acc[mi][ni], 0, 0, 0);
    }

    // ---- per-wave epilogue (wave-private LDS; DS ops are in-order per wave) ----
    float* wt = tile[wave];
#pragma unroll
    for (int mi = 0; mi < 4; ++mi) {
#pragma unroll
        for (int r = 0; r < 4; ++r) {
            int rl = mi * 16 + quad * 4 + r;
            int xr = X[(m0 + wm * 64 + rl) * 128 + t];
#pragma unroll
            for (int ni = 0; ni < 2; ++ni) {
                int cl = ni * 16 + l15;
                int cg = n0 + wn * 32 + cl;
                wt[rl * 34 + cl] = acc[mi][ni][r] + bsumP[cg] + WiP[(size_t)xr * 16384 + cg];
            }
        }
    }

    int bg = m0 + wm * 64 + lane;            // this lane's batch row
    int hx0 = (n0 + wn * 32) >> 4;           // first of the wave's 2 hx groups (even)
    u32 hvh[2], hvl[2];
#pragma unroll
    for (int u = 0; u < 2; ++u) {
        int hxg = hx0 + u;
        const float* g16 = &wt[lane * 34 + u * 16];
        float* cp = &c4[((size_t)bg * 1024 + hxg) * 4];
        float4 cc = *(const float4*)cp;
        float ca[4] = {cc.x, cc.y, cc.z, cc.w};
        float best = -3.4e38f, csel = 0.0f;
        float cn[4];
#pragma unroll
        for (int k = 0; k < 4; ++k) {
            float gi = g16[k * 4 + 0];
            float gf = g16[k * 4 + 1];
            float gg = g16[k * 4 + 2];
            float go = g16[k * 4 + 3];
            float ig = sigf(gi);
            float fg = sigf(gf);
            float tg = tanhf(gg);
            cn[k] = fg * ca[k] + ig * tg;
            if (go > best) { best = go; csel = cn[k]; }   // strict > = first max
        }
        float4 cv = {cn[0], cn[1], cn[2], cn[3]};
        *(float4*)cp = cv;
        float h = sigf(best) * tanhf(csel);
        u32 hi = bf16_rne(h);
        float hif = __uint_as_float(hi << 16);
        hvh[u] = hi;
        hvl[u] = bf16_rne(h - hif);
    }
    size_t hidx = sidx(bg, hx0);             // hx0 even -> same k-block, u32-aligned
    *(u32*)&Ohi[hidx] = hvh[0] | (hvh[1] << 16);
    *(u32*)&Olo[hidx] = hvl[0] | (hvl[1] << 16);
}

// ---------------------------------------------------------------------------
// Logits GEMM, same barrier-free register structure. Block 128x64, grid 32.
// ---------------------------------------------------------------------------
__global__ __launch_bounds__(256, 2) void gemm_logits(
    const u16* __restrict__ Ahi, const u16* __restrict__ Alo,
    const u16* __restrict__ Bhi, const u16* __restrict__ Blo,
    float* __restrict__ C, const float* __restrict__ bias)
{
    int bid = blockIdx.x;                    // 2 m x 16 n
    int m0 = (bid & 1) * 128;
    int n0 = (bid >> 1) * 64;
    int tid  = threadIdx.x;
    int lane = tid & 63;
    int wave = tid >> 6;
    int wm = wave >> 1, wn = wave & 1;
    int quad = lane >> 4, l15 = lane & 15;

    int mbase = (m0 + wm * 64) >> 4;
    int nbase = (n0 + wn * 32) >> 4;

    size_t aoff[4], boff[2];
#pragma unroll
    for (int mi = 0; mi < 4; ++mi)
        aoff[mi] = (((size_t)(mbase + mi) * 128 + quad) << 7) + (l15 << 3);
#pragma unroll
    for (int ni = 0; ni < 2; ++ni)
        boff[ni] = (((size_t)(nbase + ni) * 128 + quad) << 7) + (l15 << 3);

    f32x4 acc[4][2] = {};

#pragma unroll 2
    for (int kc = 0; kc < 32; ++kc) {
        int ko = kc * 512;
        short8 afh[4], afl[4], bfh[2], bfl[2];
#pragma unroll
        for (int mi = 0; mi < 4; ++mi) {
            afh[mi] = *(const short8*)(Ahi + aoff[mi] + ko);
            afl[mi] = *(const short8*)(Alo + aoff[mi] + ko);
        }
#pragma unroll
        for (int ni = 0; ni < 2; ++ni) {
            bfh[ni] = *(const short8*)(Bhi + boff[ni] + ko);
            bfl[ni] = *(const short8*)(Blo + boff[ni] + ko);
        }
#pragma unroll
        for (int mi = 0; mi < 4; ++mi)
#pragma unroll
            for (int ni = 0; ni < 2; ++ni)
                acc[mi][ni] = __builtin_amdgcn_mfma_f32_16x16x32_bf16(afh[mi], bfh[ni], acc[mi][ni], 0, 0, 0);
#pragma unroll
        for (int mi = 0; mi < 4; ++mi)
#pragma unroll
            for (int ni = 0; ni < 2; ++ni)
                acc[mi][ni] = __builtin_amdgcn_mfma_f32_16x16x32_bf16(afh[mi], bfl[ni], acc[mi][ni], 0, 0, 0);
#pragma unroll
        for (int mi = 0; mi < 4; ++mi)
#pragma unroll
            for (int ni = 0; ni < 2; ++ni)
                acc[mi][ni] = __builtin_amdgcn_mfma_f32_16x16x32_bf16(afl[mi], bfh[ni], acc[mi][ni], 0, 0, 0);
    }

#pragma unroll
    for (int mi = 0; mi < 4; ++mi) {
        int rbase = m0 + wm * 64 + mi * 16 + quad * 4;
#pragma unroll
        for (int ni = 0; ni < 2; ++ni) {
            int col = n0 + wn * 32 + ni * 16 + l15;
            float bv = bias[col];
#pragma unroll
            for (int r = 0; r < 4; ++r)
                C[(size_t)(rbase + r) * 1024 + col] = acc[mi][ni][r] + bv;
        }
    }
}

// ---------------------------------------------------------------------------
// Row-wise log_softmax in place over [256][1024]
// ---------------------------------------------------------------------------
__global__ __launch_bounds__(256) void logsoftmax_k(float* __restrict__ io)
{
    int b = blockIdx.x;
    float* row = io + (size_t)b * 1024;
    int tid = threadIdx.x;
    float x0 = row[tid], x1 = row[tid + 256], x2 = row[tid + 512], x3 = row[tid + 768];
    float m = fmaxf(fmaxf(x0, x1), fmaxf(x2, x3));
#pragma unroll
    for (int off = 32; off > 0; off >>= 1) m = fmaxf(m, __shfl_down(m, off, 64));
    __shared__ float sm[4], ss[4];
    if ((tid & 63) == 0) sm[tid >> 6] = m;
    __syncthreads();
    float M = fmaxf(fmaxf(sm[0], sm[1]), fmaxf(sm[2], sm[3]));
    float s = expf(x0 - M) + expf(x1 - M) + expf(x2 - M) + expf(x3 - M);
#pragma unroll
    for (int off = 32; off > 0; off >>= 1) s += __shfl_down(s, off, 64);
    if ((tid & 63) == 0) ss[tid >> 6] = s;
    __syncthreads();
    float L = M + logf(ss[0] + ss[1] + ss[2] + ss[3]);
    row[tid] = x0 - L; row[tid + 256] = x1 - L; row[tid + 512] = x2 - L; row[tid + 768] = x3 - L;
}

// ---------------------------------------------------------------------------
extern "C" void kernel_launch(void* const* d_in, const int* in_sizes, int n_in,
                              void* d_out, int out_size, void* d_ws, size_t ws_size,
                              hipStream_t stream)
{
    const int*   X  = (const int*)d_in[0];
    const float* Wi = (const float*)d_in[1];
    const float* bi = (const float*)d_in[2];
    const float* Wh = (const float*)d_in[3];
    const float* bh = (const float*)d_in[4];
    const float* Wl = (const float*)d_in[5];
    const float* bl = (const float*)d_in[6];
    float* out = (float*)d_out;

    char* p = (char*)d_ws;
    auto alloc = [&](size_t bytes) {
        char* r = p;
        p += (bytes + 255) & ~(size_t)255;
        return r;
    };
    u16*   WhTh = (u16*)alloc((size_t)16384 * 1024 * 2);
    u16*   WhTl = (u16*)alloc((size_t)16384 * 1024 * 2);
    u16*   WlTh = (u16*)alloc((size_t)1024 * 1024 * 2);
    u16*   WlTl = (u16*)alloc((size_t)1024 * 1024 * 2);
    float* WiP  = (float*)alloc((size_t)1024 * 16384 * 4);
    float* c4   = (float*)alloc((size_t)256 * 1024 * 4 * 4);
    u16*   h0h  = (u16*)alloc((size_t)262144 * 2);
    u16*   h0l  = (u16*)alloc((size_t)262144 * 2);
    u16*   h1h  = (u16*)alloc((size_t)262144 * 2);
    u16*   h1l  = (u16*)alloc((size_t)262144 * 2);
    float* bsum  = (float*)alloc((size_t)16384 * 4);
    float* bsumP = (float*)alloc((size_t)16384 * 4);

    transpose_split<true><<<dim3(256, 16), 256, 0, stream>>>(Wh, WhTh, WhTl, 16384);
    transpose_split<false><<<dim3(16, 16), 256, 0, stream>>>(Wl, WlTh, WlTl, 1024);
    permute_wi<<<dim3(4, 1024), 256, 0, stream>>>(Wi, WiP);
    init_state<<<64, 256, 0, stream>>>(bsum, bsumP, bi, bh);

    // Step 0 (h=0, c=0): writes h buffer 1
    cell0<<<512, 256, 0, stream>>>(bsum, X, Wi, c4, h1h, h1l);

    for (int t = 1; t < 128; ++t) {
        const u16* ih = (t & 1) ? h1h : h0h;
        const u16* il = (t & 1) ? h1l : h0l;
        u16* oh = (t & 1) ? h0h : h1h;
        u16* ol = (t & 1) ? h0l : h1l;
        fused_step<<<512, 256, 0, stream>>>(ih, il, WhTh, WhTl, bsumP, WiP, X, t, c4, oh, ol);
    }

    // t=127 wrote buffer 0
    gemm_logits<<<32, 256, 0, stream>>>(h0h, h0l, WlTh, WlTl, out, bl);
    logsoftmax_k<<<256, 256, 0, stream>>>(out);
}

// Round 5
// 5023.815 us; speedup vs baseline: 1.0847x; 1.0847x over previous
//
#include <hip/hip_runtime.h>
#include <hip/hip_bf16.h>

typedef unsigned short u16;
typedef unsigned int u32;
typedef __attribute__((ext_vector_type(8))) short short8;
typedef __attribute__((ext_vector_type(4))) float f32x4;

#define GLD_LDS(gptr, lptr) \
    __builtin_amdgcn_global_load_lds((const __attribute__((address_space(1))) void*)(gptr), \
                                     (__attribute__((address_space(3))) void*)(lptr), 16, 0, 0)

__device__ __forceinline__ u32 bf16_rne(float f) {
    u32 u = __float_as_uint(f);
    return (u + 0x7FFFu + ((u >> 16) & 1u)) >> 16;
}

// column permutation: orig col c = k*4096 + g*1024 + hx  ->  n = hx*16 + k*4 + g
__device__ __forceinline__ int permcol(int c) {
    return (c & 1023) * 16 + ((c >> 12) & 3) * 4 + ((c >> 10) & 3);
}

__device__ __forceinline__ float sigf(float x) { return 1.0f / (1.0f + expf(-x)); }

// ---------------------------------------------------------------------------
// Transpose + split fp32 [1024][N] -> bf16 hi/lo [N'][1024] row-major
// ---------------------------------------------------------------------------
template <bool PERM>
__global__ __launch_bounds__(256) void transpose_split(
    const float* __restrict__ W, u16* __restrict__ Thi, u16* __restrict__ Tlo, int N)
{
    __shared__ float tile[64][65];
    int n0 = blockIdx.x * 64;
    int k0 = blockIdx.y * 64;
    int tid = threadIdx.x;
    int tr = tid >> 4;      // 0..15
    int tc = tid & 15;      // 0..15
#pragma unroll
    for (int it = 0; it < 4; ++it) {
        int kr = it * 16 + tr;
        const float4* src = (const float4*)&W[(size_t)(k0 + kr) * N + n0 + tc * 4];
        float4 v = *src;
        tile[kr][tc * 4 + 0] = v.x;
        tile[kr][tc * 4 + 1] = v.y;
        tile[kr][tc * 4 + 2] = v.z;
        tile[kr][tc * 4 + 3] = v.w;
    }
    __syncthreads();
#pragma unroll
    for (int it = 0; it < 4; ++it) {
        int nr = it * 16 + tr;
        u32 h[4], l[4];
#pragma unroll
        for (int j = 0; j < 4; ++j) {
            float f = tile[tc * 4 + j][nr];
            u32 hi = bf16_rne(f);
            float hif = __uint_as_float(hi << 16);
            float lo = f - hif;
            h[j] = hi;
            l[j] = bf16_rne(lo);
        }
        int ng = n0 + nr;
        int pr = PERM ? permcol(ng) : ng;
        size_t idx = (size_t)pr * 1024 + k0 + tc * 4;
        uint2 ph, pl;
        ph.x = h[0] | (h[1] << 16); ph.y = h[2] | (h[3] << 16);
        pl.x = l[0] | (l[1] << 16); pl.y = l[2] | (l[3] << 16);
        *(uint2*)&Thi[idx] = ph;
        *(uint2*)&Tlo[idx] = pl;
    }
}

// ---------------------------------------------------------------------------
// Permute Wi columns: WiP[r][n] = Wi[r][orig(n)]
// ---------------------------------------------------------------------------
__global__ __launch_bounds__(256) void permute_wi(
    const float* __restrict__ Wi, float* __restrict__ WiP)
{
    __shared__ float l[256 * 17];
    int r = blockIdx.y, hb = blockIdx.x, tid = threadIdx.x;
    const float* src = Wi + (size_t)r * 16384;
    float* dst = WiP + (size_t)r * 16384;
#pragma unroll
    for (int kg = 0; kg < 16; ++kg) {
        int k = kg >> 2, g = kg & 3;
        l[tid * 17 + kg] = src[k * 4096 + g * 1024 + hb * 256 + tid];
    }
    __syncthreads();
#pragma unroll
    for (int it = 0; it < 16; ++it) {
        int j = it * 256 + tid;
        dst[hb * 4096 + j] = l[(j >> 4) * 17 + (j & 15)];
    }
}

// ---------------------------------------------------------------------------
// Init: bsum = bi + bh (plain and permuted)
// ---------------------------------------------------------------------------
__global__ __launch_bounds__(256) void init_state(
    float* __restrict__ bsum, float* __restrict__ bsumP,
    const float* __restrict__ bi, const float* __restrict__ bh)
{
    int i = blockIdx.x * 256 + threadIdx.x;   // 0..16383
    float v = bi[i] + bh[i];
    bsum[i] = v;
    bsumP[permcol(i)] = v;
}

// ---------------------------------------------------------------------------
// Transpose X [256][128] -> XT [128][256]
// ---------------------------------------------------------------------------
__global__ __launch_bounds__(256) void transpose_x(
    const int* __restrict__ X, int* __restrict__ XT)
{
    int t = blockIdx.x, b = threadIdx.x;
    XT[t * 256 + b] = X[b * 128 + t];
}

// ---------------------------------------------------------------------------
// Step 0: h == 0, c == 0 -> gates = bsum + Wi[X[b,0]], cell update inline.
// c4 layout: c4[(hx*256 + b)*4 ..] = float4 over k. h row-major split.
// ---------------------------------------------------------------------------
__global__ __launch_bounds__(256) void cell0(
    const float* __restrict__ bsum, const int* __restrict__ X,
    const float* __restrict__ Wi,
    float* __restrict__ c4, u16* __restrict__ Ohi, u16* __restrict__ Olo)
{
    int gid = blockIdx.x * 256 + threadIdx.x;   // 0..262143
    int b = gid & 255, hx = gid >> 8;
    int xr = X[b * 128];
    const float* wr = Wi + (size_t)xr * 16384;
    float best = -3.4e38f, csel = 0.0f;
    float cn[4];
#pragma unroll
    for (int k = 0; k < 4; ++k) {
        int base = k * 4096 + hx;
        float gi = bsum[base + 0]    + wr[base + 0];
        float gf = bsum[base + 1024] + wr[base + 1024];
        float gg = bsum[base + 2048] + wr[base + 2048];
        float go = bsum[base + 3072] + wr[base + 3072];
        float ig = sigf(gi);
        float fg = sigf(gf); (void)fg;           // c_old = 0
        float tg = tanhf(gg);
        cn[k] = ig * tg;
        if (go > best) { best = go; csel = cn[k]; }
    }
    float4 cv = {cn[0], cn[1], cn[2], cn[3]};
    *(float4*)&c4[((size_t)hx * 256 + b) * 4] = cv;
    float h = sigf(best) * tanhf(csel);
    u32 hi = bf16_rne(h);
    float hif = __uint_as_float(hi << 16);
    u32 lo = bf16_rne(h - hif);
    Ohi[(size_t)b * 1024 + hx] = (u16)hi;
    Olo[(size_t)b * 1024 + hx] = (u16)lo;
}

// ---------------------------------------------------------------------------
// Fused step: gates GEMM (bf16x3, permuted cols) + cell update.
// BM=128, BN=64, BK=32; 512 threads = 8 waves (4m x 2n), wave tile 32x32
// (acc 2x2). grid 512 -> 2 blocks/CU -> 16 waves/CU. LDS 48 KB dbuf.
// Epilogue: raw acc -> per-wave LDS tile (stride 35) -> per-lane cell math
// with float4 WiP/bias adds, coalesced c4 (hx-major).
// ---------------------------------------------------------------------------
__global__ __launch_bounds__(512, 4) void fused_step(
    const u16* __restrict__ Ahi, const u16* __restrict__ Alo,
    const u16* __restrict__ Bhi, const u16* __restrict__ Blo,
    const float* __restrict__ bsumP, const float* __restrict__ WiP,
    const int* __restrict__ XT, int t,
    float* __restrict__ c4, u16* __restrict__ Ohi, u16* __restrict__ Olo)
{
    constexpr int KD = 1024;
    // per buf (u16): Ahi [0,4096) Alo [4096,8192) Bhi [8192,10240) Blo [10240,12288)
    __shared__ __align__(16) char smem[49152];
    u16* lds = (u16*)smem;
    float* tileb = (float*)smem;   // epilogue: 8 waves x 32x35 floats = 35840 B

    int bid = blockIdx.x;
    int xcd = bid & 7, rr = bid >> 3;
    int m0 = (rr & 1) * 128;
    int n0 = ((rr >> 1) * 8 + xcd) * 64;
    int tid  = threadIdx.x;
    int lane = tid & 63;
    int wave = tid >> 6;               // 0..7
    int wm = wave >> 1, wn = wave & 1; // 4m x 2n
    int quad = lane >> 4, l15 = lane & 15;

    f32x4 acc[2][2] = {};

    auto stage = [&](int buf, int kc) {
        int k0 = kc * 32;
        int base = buf * 12288;
        {   // A: 128 rows x 4 segs x 2 arrays = 1024 loads (2/thread)
            int row = tid >> 2, s = tid & 3;
            size_t ga = (size_t)(m0 + row) * KD + k0 + s * 8;
            GLD_LDS(Ahi + ga, &lds[base + 0    + tid * 8]);
            GLD_LDS(Alo + ga, &lds[base + 4096 + tid * 8]);
        }
        {   // B: 64 rows x 4 segs x 2 arrays = 512 loads (1/thread)
            int q = tid & 255;
            int row = q >> 2, s = q & 3;
            size_t gb = (size_t)(n0 + row) * KD + k0 + s * 8;
            if (tid < 256) GLD_LDS(Bhi + gb, &lds[base + 8192  + q * 8]);
            else           GLD_LDS(Blo + gb, &lds[base + 10240 + q * 8]);
        }
    };

    stage(0, 0);
    constexpr int NK = KD / 32;
    for (int kc = 0; kc < NK; ++kc) {
        __syncthreads();
        if (kc + 1 < NK) stage((kc + 1) & 1, kc + 1);
        int base = (kc & 1) * 12288;

        short8 afh[2], afl[2], bfh[2], bfl[2];
#pragma unroll
        for (int mi = 0; mi < 2; ++mi) {
            int ar = wm * 32 + mi * 16 + l15;
            afh[mi] = *(const short8*)&lds[base + 0    + ar * 32 + quad * 8];
            afl[mi] = *(const short8*)&lds[base + 4096 + ar * 32 + quad * 8];
        }
#pragma unroll
        for (int ni = 0; ni < 2; ++ni) {
            int br = wn * 32 + ni * 16 + l15;
            bfh[ni] = *(const short8*)&lds[base + 8192  + br * 32 + quad * 8];
            bfl[ni] = *(const short8*)&lds[base + 10240 + br * 32 + quad * 8];
        }
        // term-major: 4 independent MFMAs/burst; per-acc order hh, hl, lh
#pragma unroll
        for (int mi = 0; mi < 2; ++mi)
#pragma unroll
            for (int ni = 0; ni < 2; ++ni)
                acc[mi][ni] = __builtin_amdgcn_mfma_f32_16x16x32_bf16(afh[mi], bfh[ni], acc[mi][ni], 0, 0, 0);
#pragma unroll
        for (int mi = 0; mi < 2; ++mi)
#pragma unroll
            for (int ni = 0; ni < 2; ++ni)
                acc[mi][ni] = __builtin_amdgcn_mfma_f32_16x16x32_bf16(afh[mi], bfl[ni], acc[mi][ni], 0, 0, 0);
#pragma unroll
        for (int mi = 0; mi < 2; ++mi)
#pragma unroll
            for (int ni = 0; ni < 2; ++ni)
                acc[mi][ni] = __builtin_amdgcn_mfma_f32_16x16x32_bf16(afl[mi], bfh[ni], acc[mi][ni], 0, 0, 0);
    }

    __syncthreads();   // staging LDS -> epilogue tile reuse (cross-wave region overlap)

    // Phase 1: raw acc -> per-wave tile [32][35]
    float* wt = tileb + wave * (32 * 35);
#pragma unroll
    for (int mi = 0; mi < 2; ++mi)
#pragma unroll
        for (int ni = 0; ni < 2; ++ni)
#pragma unroll
            for (int r = 0; r < 4; ++r) {
                int rl = mi * 16 + quad * 4 + r;
                int cl = ni * 16 + l15;
                wt[rl * 35 + cl] = acc[mi][ni][r];
            }

    // Phase 2: per-lane cell update. lane -> row (lane&31), hx half (lane>>5)
    int bl = lane & 31;
    int bg = m0 + wm * 32 + bl;
    int u  = lane >> 5;
    int hxg = ((n0 + wn * 32) >> 4) + u;         // == hx (0..1023)
    int xr = XT[t * 256 + bg];

    const float* g16 = &wt[bl * 35 + u * 16];
    const float4* wip = (const float4*)&WiP[(size_t)xr * 16384 + hxg * 16];
    const float4* bsp = (const float4*)&bsumP[hxg * 16];

    float* cp = &c4[((size_t)hxg * 256 + bg) * 4];
    float4 cc = *(const float4*)cp;
    float ca[4] = {cc.x, cc.y, cc.z, cc.w};
    float best = -3.4e38f, csel = 0.0f;
    float cn[4];
#pragma unroll
    for (int k = 0; k < 4; ++k) {
        float4 wv = wip[k];
        float4 bv = bsp[k];
        float gi = (g16[k * 4 + 0] + bv.x) + wv.x;
        float gf = (g16[k * 4 + 1] + bv.y) + wv.y;
        float gg = (g16[k * 4 + 2] + bv.z) + wv.z;
        float go = (g16[k * 4 + 3] + bv.w) + wv.w;
        float ig = sigf(gi);
        float fg = sigf(gf);
        float tg = tanhf(gg);
        cn[k] = fg * ca[k] + ig * tg;
        if (go > best) { best = go; csel = cn[k]; }   // strict > = first max
    }
    float4 cv = {cn[0], cn[1], cn[2], cn[3]};
    *(float4*)cp = cv;
    float h = sigf(best) * tanhf(csel);
    u32 hi = bf16_rne(h);
    float hif = __uint_as_float(hi << 16);
    u32 lo = bf16_rne(h - hif);
    Ohi[(size_t)bg * 1024 + hxg] = (u16)hi;
    Olo[(size_t)bg * 1024 + hxg] = (u16)lo;
}

// ---------------------------------------------------------------------------
// Logits GEMM (round-3 LDS structure): C[256][1024] = h @ Wl + bl.
// BM=128, BN=128, grid 16, 256 threads.
// ---------------------------------------------------------------------------
__global__ __launch_bounds__(256) void gemm_logits(
    const u16* __restrict__ Ahi, const u16* __restrict__ Alo,
    const u16* __restrict__ Bhi, const u16* __restrict__ Blo,
    float* __restrict__ C, const float* __restrict__ bias)
{
    constexpr int KD = 1024;
    __shared__ u16 lds[2][16384];
    int bid = blockIdx.x;
    int xcd = bid & 7, g = bid >> 3;
    int m0 = g * 128;
    int n0 = xcd * 128;
    int tid  = threadIdx.x;
    int lane = tid & 63;
    int wave = tid >> 6;
    int wm = wave >> 1, wn = wave & 1;
    int quad = lane >> 4, l15 = lane & 15;

    f32x4 acc[4][4] = {};

    auto stage = [&](int buf, int kc) {
        int k0 = kc * 32;
#pragma unroll
        for (int j = 0; j < 2; ++j) {
            int seg = j * 256 + tid;
            int row = seg >> 2, s = seg & 3;
            size_t ga = (size_t)(m0 + row) * KD + k0 + s * 8;
            GLD_LDS(Ahi + ga, &lds[buf][0    + seg * 8]);
            GLD_LDS(Alo + ga, &lds[buf][4096 + seg * 8]);
            size_t gb = (size_t)(n0 + row) * KD + k0 + s * 8;
            GLD_LDS(Bhi + gb, &lds[buf][8192  + seg * 8]);
            GLD_LDS(Blo + gb, &lds[buf][12288 + seg * 8]);
        }
    };

    stage(0, 0);
    constexpr int NK = KD / 32;
    for (int kc = 0; kc < NK; ++kc) {
        __syncthreads();
        if (kc + 1 < NK) stage((kc + 1) & 1, kc + 1);
        int buf = kc & 1;
        short8 afh[4], afl[4], bfh[4], bfl[4];
#pragma unroll
        for (int i = 0; i < 4; ++i) {
            int ar = wm * 64 + i * 16 + l15;
            afh[i] = *(const short8*)&lds[buf][0    + ar * 32 + quad * 8];
            afl[i] = *(const short8*)&lds[buf][4096 + ar * 32 + quad * 8];
            int br = wn * 64 + i * 16 + l15;
            bfh[i] = *(const short8*)&lds[buf][8192  + br * 32 + quad * 8];
            bfl[i] = *(const short8*)&lds[buf][12288 + br * 32 + quad * 8];
        }
#pragma unroll
        for (int mi = 0; mi < 4; ++mi)
#pragma unroll
            for (int ni = 0; ni < 4; ++ni)
                acc[mi][ni] = __builtin_amdgcn_mfma_f32_16x16x32_bf16(afh[mi], bfh[ni], acc[mi][ni], 0, 0, 0);
#pragma unroll
        for (int mi = 0; mi < 4; ++mi)
#pragma unroll
            for (int ni = 0; ni < 4; ++ni)
                acc[mi][ni] = __builtin_amdgcn_mfma_f32_16x16x32_bf16(afh[mi], bfl[ni], acc[mi][ni], 0, 0, 0);
#pragma unroll
        for (int mi = 0; mi < 4; ++mi)
#pragma unroll
            for (int ni = 0; ni < 4; ++ni)
                acc[mi][ni] = __builtin_amdgcn_mfma_f32_16x16x32_bf16(afl[mi], bfh[ni], acc[mi][ni], 0, 0, 0);
    }

#pragma unroll
    for (int mi = 0; mi < 4; ++mi) {
        int rbase = m0 + wm * 64 + mi * 16 + quad * 4;
#pragma unroll
        for (int ni = 0; ni < 4; ++ni) {
            int col = n0 + wn * 64 + ni * 16 + l15;
            float bv = bias[col];
#pragma unroll
            for (int r = 0; r < 4; ++r)
                C[(size_t)(rbase + r) * 1024 + col] = acc[mi][ni][r] + bv;
        }
    }
}

// ---------------------------------------------------------------------------
// Row-wise log_softmax in place over [256][1024]
// ---------------------------------------------------------------------------
__global__ __launch_bounds__(256) void logsoftmax_k(float* __restrict__ io)
{
    int b = blockIdx.x;
    float* row = io + (size_t)b * 1024;
    int tid = threadIdx.x;
    float x0 = row[tid], x1 = row[tid + 256], x2 = row[tid + 512], x3 = row[tid + 768];
    float m = fmaxf(fmaxf(x0, x1), fmaxf(x2, x3));
#pragma unroll
    for (int off = 32; off > 0; off >>= 1) m = fmaxf(m, __shfl_down(m, off, 64));
    __shared__ float sm[4], ss[4];
    if ((tid & 63) == 0) sm[tid >> 6] = m;
    __syncthreads();
    float M = fmaxf(fmaxf(sm[0], sm[1]), fmaxf(sm[2], sm[3]));
    float s = expf(x0 - M) + expf(x1 - M) + expf(x2 - M) + expf(x3 - M);
#pragma unroll
    for (int off = 32; off > 0; off >>= 1) s += __shfl_down(s, off, 64);
    if ((tid & 63) == 0) ss[tid >> 6] = s;
    __syncthreads();
    float L = M + logf(ss[0] + ss[1] + ss[2] + ss[3]);
    row[tid] = x0 - L; row[tid + 256] = x1 - L; row[tid + 512] = x2 - L; row[tid + 768] = x3 - L;
}

// ---------------------------------------------------------------------------
extern "C" void kernel_launch(void* const* d_in, const int* in_sizes, int n_in,
                              void* d_out, int out_size, void* d_ws, size_t ws_size,
                              hipStream_t stream)
{
    const int*   X  = (const int*)d_in[0];
    const float* Wi = (const float*)d_in[1];
    const float* bi = (const float*)d_in[2];
    const float* Wh = (const float*)d_in[3];
    const float* bh = (const float*)d_in[4];
    const float* Wl = (const float*)d_in[5];
    const float* bl = (const float*)d_in[6];
    float* out = (float*)d_out;

    char* p = (char*)d_ws;
    auto alloc = [&](size_t bytes) {
        char* r = p;
        p += (bytes + 255) & ~(size_t)255;
        return r;
    };
    u16*   WhTh = (u16*)alloc((size_t)16384 * 1024 * 2);
    u16*   WhTl = (u16*)alloc((size_t)16384 * 1024 * 2);
    u16*   WlTh = (u16*)alloc((size_t)1024 * 1024 * 2);
    u16*   WlTl = (u16*)alloc((size_t)1024 * 1024 * 2);
    float* WiP  = (float*)alloc((size_t)1024 * 16384 * 4);
    float* c4   = (float*)alloc((size_t)256 * 1024 * 4 * 4);
    u16*   h0h  = (u16*)alloc((size_t)262144 * 2);
    u16*   h0l  = (u16*)alloc((size_t)262144 * 2);
    u16*   h1h  = (u16*)alloc((size_t)262144 * 2);
    u16*   h1l  = (u16*)alloc((size_t)262144 * 2);
    float* bsum  = (float*)alloc((size_t)16384 * 4);
    float* bsumP = (float*)alloc((size_t)16384 * 4);
    int*   XT    = (int*)alloc((size_t)128 * 256 * 4);

    transpose_split<true><<<dim3(256, 16), 256, 0, stream>>>(Wh, WhTh, WhTl, 16384);
    transpose_split<false><<<dim3(16, 16), 256, 0, stream>>>(Wl, WlTh, WlTl, 1024);
    permute_wi<<<dim3(4, 1024), 256, 0, stream>>>(Wi, WiP);
    init_state<<<64, 256, 0, stream>>>(bsum, bsumP, bi, bh);
    transpose_x<<<128, 256, 0, stream>>>(X, XT);

    // Step 0 (h=0, c=0): writes h buffer 1
    cell0<<<1024, 256, 0, stream>>>(bsum, X, Wi, c4, h1h, h1l);

    for (int t = 1; t < 128; ++t) {
        const u16* ih = (t & 1) ? h1h : h0h;
        const u16* il = (t & 1) ? h1l : h0l;
        u16* oh = (t & 1) ? h0h : h1h;
        u16* ol = (t & 1) ? h0l : h1l;
        fused_step<<<512, 512, 0, stream>>>(ih, il, WhTh, WhTl, bsumP, WiP, XT, t, c4, oh, ol);
    }

    // t=127 wrote buffer 0
    gemm_logits<<<16, 256, 0, stream>>>(h0h, h0l, WlTh, WlTl, out, bl);
    logsoftmax_k<<<256, 256, 0, stream>>>(out);
}

// Round 6
// 4742.466 us; speedup vs baseline: 1.1491x; 1.0593x over previous
//
#include <hip/hip_runtime.h>
#include <hip/hip_bf16.h>

typedef unsigned short u16;
typedef unsigned int u32;
typedef __attribute__((ext_vector_type(8))) short short8;
typedef __attribute__((ext_vector_type(4))) float f32x4;

#define GLD_LDS(gptr, lptr) \
    __builtin_amdgcn_global_load_lds((const __attribute__((address_space(1))) void*)(gptr), \
                                     (__attribute__((address_space(3))) void*)(lptr), 16, 0, 0)

__device__ __forceinline__ u32 bf16_rne(float f) {
    u32 u = __float_as_uint(f);
    return (u + 0x7FFFu + ((u >> 16) & 1u)) >> 16;
}

// column permutation: orig col c = k*4096 + g*1024 + hx  ->  n = hx*16 + k*4 + g
__device__ __forceinline__ int permcol(int c) {
    return (c & 1023) * 16 + ((c >> 12) & 3) * 4 + ((c >> 10) & 3);
}

__device__ __forceinline__ float sigf(float x) { return 1.0f / (1.0f + expf(-x)); }

// ---------------------------------------------------------------------------
// Transpose + split fp32 [1024][N] -> bf16 hi/lo [N'][1024] row-major
// ---------------------------------------------------------------------------
template <bool PERM>
__global__ __launch_bounds__(256) void transpose_split(
    const float* __restrict__ W, u16* __restrict__ Thi, u16* __restrict__ Tlo, int N)
{
    __shared__ float tile[64][65];
    int n0 = blockIdx.x * 64;
    int k0 = blockIdx.y * 64;
    int tid = threadIdx.x;
    int tr = tid >> 4;      // 0..15
    int tc = tid & 15;      // 0..15
#pragma unroll
    for (int it = 0; it < 4; ++it) {
        int kr = it * 16 + tr;
        const float4* src = (const float4*)&W[(size_t)(k0 + kr) * N + n0 + tc * 4];
        float4 v = *src;
        tile[kr][tc * 4 + 0] = v.x;
        tile[kr][tc * 4 + 1] = v.y;
        tile[kr][tc * 4 + 2] = v.z;
        tile[kr][tc * 4 + 3] = v.w;
    }
    __syncthreads();
#pragma unroll
    for (int it = 0; it < 4; ++it) {
        int nr = it * 16 + tr;
        u32 h[4], l[4];
#pragma unroll
        for (int j = 0; j < 4; ++j) {
            float f = tile[tc * 4 + j][nr];
            u32 hi = bf16_rne(f);
            float hif = __uint_as_float(hi << 16);
            float lo = f - hif;
            h[j] = hi;
            l[j] = bf16_rne(lo);
        }
        int ng = n0 + nr;
        int pr = PERM ? permcol(ng) : ng;
        size_t idx = (size_t)pr * 1024 + k0 + tc * 4;
        uint2 ph, pl;
        ph.x = h[0] | (h[1] << 16); ph.y = h[2] | (h[3] << 16);
        pl.x = l[0] | (l[1] << 16); pl.y = l[2] | (l[3] << 16);
        *(uint2*)&Thi[idx] = ph;
        *(uint2*)&Tlo[idx] = pl;
    }
}

// ---------------------------------------------------------------------------
// Permute Wi columns: WiP[r][n] = Wi[r][orig(n)]
// ---------------------------------------------------------------------------
__global__ __launch_bounds__(256) void permute_wi(
    const float* __restrict__ Wi, float* __restrict__ WiP)
{
    __shared__ float l[256 * 17];
    int r = blockIdx.y, hb = blockIdx.x, tid = threadIdx.x;
    const float* src = Wi + (size_t)r * 16384;
    float* dst = WiP + (size_t)r * 16384;
#pragma unroll
    for (int kg = 0; kg < 16; ++kg) {
        int k = kg >> 2, g = kg & 3;
        l[tid * 17 + kg] = src[k * 4096 + g * 1024 + hb * 256 + tid];
    }
    __syncthreads();
#pragma unroll
    for (int it = 0; it < 16; ++it) {
        int j = it * 256 + tid;
        dst[hb * 4096 + j] = l[(j >> 4) * 17 + (j & 15)];
    }
}

// ---------------------------------------------------------------------------
// Init: bsum = bi + bh (plain and permuted)
// ---------------------------------------------------------------------------
__global__ __launch_bounds__(256) void init_state(
    float* __restrict__ bsum, float* __restrict__ bsumP,
    const float* __restrict__ bi, const float* __restrict__ bh)
{
    int i = blockIdx.x * 256 + threadIdx.x;   // 0..16383
    float v = bi[i] + bh[i];
    bsum[i] = v;
    bsumP[permcol(i)] = v;
}

// ---------------------------------------------------------------------------
// Transpose X [256][128] -> XT [128][256]
// ---------------------------------------------------------------------------
__global__ __launch_bounds__(256) void transpose_x(
    const int* __restrict__ X, int* __restrict__ XT)
{
    int t = blockIdx.x, b = threadIdx.x;
    XT[t * 256 + b] = X[b * 128 + t];
}

// ---------------------------------------------------------------------------
// Step 0: h == 0, c == 0 -> gates = bsum + Wi[X[b,0]], cell update inline.
// c4 layout: c4[(hx*256 + b)*4 ..] = float4 over k. h row-major split.
// ---------------------------------------------------------------------------
__global__ __launch_bounds__(256) void cell0(
    const float* __restrict__ bsum, const int* __restrict__ X,
    const float* __restrict__ Wi,
    float* __restrict__ c4, u16* __restrict__ Ohi, u16* __restrict__ Olo)
{
    int gid = blockIdx.x * 256 + threadIdx.x;   // 0..262143
    int b = gid & 255, hx = gid >> 8;
    int xr = X[b * 128];
    const float* wr = Wi + (size_t)xr * 16384;
    float best = -3.4e38f, csel = 0.0f;
    float cn[4];
#pragma unroll
    for (int k = 0; k < 4; ++k) {
        int base = k * 4096 + hx;
        float gi = bsum[base + 0]    + wr[base + 0];
        float gf = bsum[base + 1024] + wr[base + 1024];
        float gg = bsum[base + 2048] + wr[base + 2048];
        float go = bsum[base + 3072] + wr[base + 3072];
        float ig = sigf(gi);
        float fg = sigf(gf); (void)fg;           // c_old = 0
        float tg = tanhf(gg);
        cn[k] = ig * tg;
        if (go > best) { best = go; csel = cn[k]; }
    }
    float4 cv = {cn[0], cn[1], cn[2], cn[3]};
    *(float4*)&c4[((size_t)hx * 256 + b) * 4] = cv;
    float h = sigf(best) * tanhf(csel);
    u32 hi = bf16_rne(h);
    float hif = __uint_as_float(hi << 16);
    u32 lo = bf16_rne(h - hif);
    Ohi[(size_t)b * 1024 + hx] = (u16)hi;
    Olo[(size_t)b * 1024 + hx] = (u16)lo;
}

// ---------------------------------------------------------------------------
// Fused step: gates GEMM (bf16x3, permuted cols) + cell update.
// BM=128, BN=128, BK=32; 512 threads = 8 waves (2m x 4n), wave tile 64x32
// (acc 4x2). grid 256 -> 1 block/CU, high tile intensity:
// per CU-chunk: 32 KB L2-inbound, 32 KB LDS-write, 96 KB LDS-read, 930 cyc MFMA.
// Bank-conflict-free frag reads via k-segment rotation sg=(s+(row>>1))&3
// applied on the GLOBAL side (LDS dest stays lane-ordered for global_load_lds).
// ---------------------------------------------------------------------------
__global__ __launch_bounds__(512, 2) void fused_step(
    const u16* __restrict__ Ahi, const u16* __restrict__ Alo,
    const u16* __restrict__ Bhi, const u16* __restrict__ Blo,
    const float* __restrict__ bsumP, const float* __restrict__ WiP,
    const int* __restrict__ XT, int t,
    float* __restrict__ c4, u16* __restrict__ Ohi, u16* __restrict__ Olo)
{
    constexpr int KD = 1024;
    // staging per buf (u16): Ahi [0,4096) Alo [4096,8192) Bhi [8192,12288) Blo [12288,16384)
    // epilogue: 8 wave-private tiles 64x33 floats = 67584 B total
    __shared__ __align__(16) char smem[67584];
    u16* lds = (u16*)smem;
    float* tileb = (float*)smem;

    int bid = blockIdx.x;
    int xcd = bid & 7, rr = bid >> 3;           // rr 0..31
    int m0 = (rr & 1) * 128;
    int n0 = (((rr >> 1) * 8) + xcd) * 128;     // 0..16256
    int tid  = threadIdx.x;
    int lane = tid & 63;
    int wave = tid >> 6;                        // 0..7
    int wm = wave >> 2, wn = wave & 3;          // 2m x 4n
    int quad = lane >> 4, l15 = lane & 15;

    f32x4 acc[4][2] = {};

    int srow = tid >> 2, ss = tid & 3;
    int sg = (ss + (srow >> 1)) & 3;            // rotated k-segment (global side)
    auto stage = [&](int buf, int kc) {
        int k0 = kc * 32;
        int base = buf * 16384;
        size_t ga = (size_t)(m0 + srow) * KD + k0 + sg * 8;
        size_t gb = (size_t)(n0 + srow) * KD + k0 + sg * 8;
        GLD_LDS(Ahi + ga, &lds[base + 0     + tid * 8]);
        GLD_LDS(Alo + ga, &lds[base + 4096  + tid * 8]);
        GLD_LDS(Bhi + gb, &lds[base + 8192  + tid * 8]);
        GLD_LDS(Blo + gb, &lds[base + 12288 + tid * 8]);
    };

    // frag read offsets (un-rotate the segment): phys = (quad - (row>>1)) & 3
    int aro[4], bro[2];
#pragma unroll
    for (int mi = 0; mi < 4; ++mi) {
        int ar = wm * 64 + mi * 16 + l15;       // 0..127
        aro[mi] = ar * 32 + (((quad - (ar >> 1)) & 3) * 8);
    }
#pragma unroll
    for (int ni = 0; ni < 2; ++ni) {
        int br = wn * 32 + ni * 16 + l15;       // 0..127
        bro[ni] = br * 32 + (((quad - (br >> 1)) & 3) * 8);
    }

    stage(0, 0);
    constexpr int NK = KD / 32;
    for (int kc = 0; kc < NK; ++kc) {
        __syncthreads();
        if (kc + 1 < NK) stage((kc + 1) & 1, kc + 1);
        int base = (kc & 1) * 16384;

        short8 afh[4], afl[4], bfh[2], bfl[2];
#pragma unroll
        for (int mi = 0; mi < 4; ++mi) {
            afh[mi] = *(const short8*)&lds[base + 0    + aro[mi]];
            afl[mi] = *(const short8*)&lds[base + 4096 + aro[mi]];
        }
#pragma unroll
        for (int ni = 0; ni < 2; ++ni) {
            bfh[ni] = *(const short8*)&lds[base + 8192  + bro[ni]];
            bfl[ni] = *(const short8*)&lds[base + 12288 + bro[ni]];
        }
        // term-major: 8 independent MFMAs per burst; per-acc order hh, hl, lh
#pragma unroll
        for (int mi = 0; mi < 4; ++mi)
#pragma unroll
            for (int ni = 0; ni < 2; ++ni)
                acc[mi][ni] = __builtin_amdgcn_mfma_f32_16x16x32_bf16(afh[mi], bfh[ni], acc[mi][ni], 0, 0, 0);
#pragma unroll
        for (int mi = 0; mi < 4; ++mi)
#pragma unroll
            for (int ni = 0; ni < 2; ++ni)
                acc[mi][ni] = __builtin_amdgcn_mfma_f32_16x16x32_bf16(afh[mi], bfl[ni], acc[mi][ni], 0, 0, 0);
#pragma unroll
        for (int mi = 0; mi < 4; ++mi)
#pragma unroll
            for (int ni = 0; ni < 2; ++ni)
                acc[mi][ni] = __builtin_amdgcn_mfma_f32_16x16x32_bf16(afl[mi], bfh[ni], acc[mi][ni], 0, 0, 0);
    }

    __syncthreads();   // staging region -> epilogue tile reuse

    // Phase 1: raw acc -> wave-private tile [64][33]
    float* wt = tileb + wave * (64 * 33);
#pragma unroll
    for (int mi = 0; mi < 4; ++mi)
#pragma unroll
        for (int ni = 0; ni < 2; ++ni)
#pragma unroll
            for (int r = 0; r < 4; ++r) {
                int rl = mi * 16 + quad * 4 + r;    // 0..63
                int cl = ni * 16 + l15;             // 0..31
                wt[rl * 33 + cl] = acc[mi][ni][r];
            }

    // Phase 2: per-lane cell update. lane -> row; two hx groups per lane.
    int bg = m0 + wm * 64 + lane;
    int hxbase = (n0 + wn * 32) >> 4;
    int xr = XT[t * 256 + bg];
#pragma unroll
    for (int u = 0; u < 2; ++u) {
        int hxg = hxbase + u;
        const float* g16 = &wt[lane * 33 + u * 16];
        const float4* wip = (const float4*)&WiP[(size_t)xr * 16384 + hxg * 16];
        const float4* bsp = (const float4*)&bsumP[hxg * 16];
        float* cp = &c4[((size_t)hxg * 256 + bg) * 4];
        float4 cc = *(const float4*)cp;
        float ca[4] = {cc.x, cc.y, cc.z, cc.w};
        float best = -3.4e38f, csel = 0.0f;
        float cn[4];
#pragma unroll
        for (int k = 0; k < 4; ++k) {
            float4 wv = wip[k];
            float4 bv = bsp[k];
            float gi = (g16[k * 4 + 0] + bv.x) + wv.x;
            float gf = (g16[k * 4 + 1] + bv.y) + wv.y;
            float gg = (g16[k * 4 + 2] + bv.z) + wv.z;
            float go = (g16[k * 4 + 3] + bv.w) + wv.w;
            float ig = sigf(gi);
            float fg = sigf(gf);
            float tg = tanhf(gg);
            cn[k] = fg * ca[k] + ig * tg;
            if (go > best) { best = go; csel = cn[k]; }   // strict > = first max
        }
        float4 cv = {cn[0], cn[1], cn[2], cn[3]};
        *(float4*)cp = cv;
        float h = sigf(best) * tanhf(csel);
        u32 hi = bf16_rne(h);
        float hif = __uint_as_float(hi << 16);
        u32 lo = bf16_rne(h - hif);
        Ohi[(size_t)bg * 1024 + hxg] = (u16)hi;
        Olo[(size_t)bg * 1024 + hxg] = (u16)lo;
    }
}

// ---------------------------------------------------------------------------
// Logits GEMM (LDS structure): C[256][1024] = h @ Wl + bl. BM=128,BN=128, grid 16.
// ---------------------------------------------------------------------------
__global__ __launch_bounds__(256) void gemm_logits(
    const u16* __restrict__ Ahi, const u16* __restrict__ Alo,
    const u16* __restrict__ Bhi, const u16* __restrict__ Blo,
    float* __restrict__ C, const float* __restrict__ bias)
{
    constexpr int KD = 1024;
    __shared__ u16 lds[2][16384];
    int bid = blockIdx.x;
    int xcd = bid & 7, g = bid >> 3;
    int m0 = g * 128;
    int n0 = xcd * 128;
    int tid  = threadIdx.x;
    int lane = tid & 63;
    int wave = tid >> 6;
    int wm = wave >> 1, wn = wave & 1;
    int quad = lane >> 4, l15 = lane & 15;

    f32x4 acc[4][4] = {};

    auto stage = [&](int buf, int kc) {
        int k0 = kc * 32;
#pragma unroll
        for (int j = 0; j < 2; ++j) {
            int seg = j * 256 + tid;
            int row = seg >> 2, s = seg & 3;
            size_t ga = (size_t)(m0 + row) * KD + k0 + s * 8;
            GLD_LDS(Ahi + ga, &lds[buf][0    + seg * 8]);
            GLD_LDS(Alo + ga, &lds[buf][4096 + seg * 8]);
            size_t gb = (size_t)(n0 + row) * KD + k0 + s * 8;
            GLD_LDS(Bhi + gb, &lds[buf][8192  + seg * 8]);
            GLD_LDS(Blo + gb, &lds[buf][12288 + seg * 8]);
        }
    };

    stage(0, 0);
    constexpr int NK = KD / 32;
    for (int kc = 0; kc < NK; ++kc) {
        __syncthreads();
        if (kc + 1 < NK) stage((kc + 1) & 1, kc + 1);
        int buf = kc & 1;
        short8 afh[4], afl[4], bfh[4], bfl[4];
#pragma unroll
        for (int i = 0; i < 4; ++i) {
            int ar = wm * 64 + i * 16 + l15;
            afh[i] = *(const short8*)&lds[buf][0    + ar * 32 + quad * 8];
            afl[i] = *(const short8*)&lds[buf][4096 + ar * 32 + quad * 8];
            int br = wn * 64 + i * 16 + l15;
            bfh[i] = *(const short8*)&lds[buf][8192  + br * 32 + quad * 8];
            bfl[i] = *(const short8*)&lds[buf][12288 + br * 32 + quad * 8];
        }
#pragma unroll
        for (int mi = 0; mi < 4; ++mi)
#pragma unroll
            for (int ni = 0; ni < 4; ++ni)
                acc[mi][ni] = __builtin_amdgcn_mfma_f32_16x16x32_bf16(afh[mi], bfh[ni], acc[mi][ni], 0, 0, 0);
#pragma unroll
        for (int mi = 0; mi < 4; ++mi)
#pragma unroll
            for (int ni = 0; ni < 4; ++ni)
                acc[mi][ni] = __builtin_amdgcn_mfma_f32_16x16x32_bf16(afh[mi], bfl[ni], acc[mi][ni], 0, 0, 0);
#pragma unroll
        for (int mi = 0; mi < 4; ++mi)
#pragma unroll
            for (int ni = 0; ni < 4; ++ni)
                acc[mi][ni] = __builtin_amdgcn_mfma_f32_16x16x32_bf16(afl[mi], bfh[ni], acc[mi][ni], 0, 0, 0);
    }

#pragma unroll
    for (int mi = 0; mi < 4; ++mi) {
        int rbase = m0 + wm * 64 + mi * 16 + quad * 4;
#pragma unroll
        for (int ni = 0; ni < 4; ++ni) {
            int col = n0 + wn * 64 + ni * 16 + l15;
            float bv = bias[col];
#pragma unroll
            for (int r = 0; r < 4; ++r)
                C[(size_t)(rbase + r) * 1024 + col] = acc[mi][ni][r] + bv;
        }
    }
}

// ---------------------------------------------------------------------------
// Row-wise log_softmax in place over [256][1024]
// ---------------------------------------------------------------------------
__global__ __launch_bounds__(256) void logsoftmax_k(float* __restrict__ io)
{
    int b = blockIdx.x;
    float* row = io + (size_t)b * 1024;
    int tid = threadIdx.x;
    float x0 = row[tid], x1 = row[tid + 256], x2 = row[tid + 512], x3 = row[tid + 768];
    float m = fmaxf(fmaxf(x0, x1), fmaxf(x2, x3));
#pragma unroll
    for (int off = 32; off > 0; off >>= 1) m = fmaxf(m, __shfl_down(m, off, 64));
    __shared__ float sm[4], ss[4];
    if ((tid & 63) == 0) sm[tid >> 6] = m;
    __syncthreads();
    float M = fmaxf(fmaxf(sm[0], sm[1]), fmaxf(sm[2], sm[3]));
    float s = expf(x0 - M) + expf(x1 - M) + expf(x2 - M) + expf(x3 - M);
#pragma unroll
    for (int off = 32; off > 0; off >>= 1) s += __shfl_down(s, off, 64);
    if ((tid & 63) == 0) ss[tid >> 6] = s;
    __syncthreads();
    float L = M + logf(ss[0] + ss[1] + ss[2] + ss[3]);
    row[tid] = x0 - L; row[tid + 256] = x1 - L; row[tid + 512] = x2 - L; row[tid + 768] = x3 - L;
}

// ---------------------------------------------------------------------------
extern "C" void kernel_launch(void* const* d_in, const int* in_sizes, int n_in,
                              void* d_out, int out_size, void* d_ws, size_t ws_size,
                              hipStream_t stream)
{
    const int*   X  = (const int*)d_in[0];
    const float* Wi = (const float*)d_in[1];
    const float* bi = (const float*)d_in[2];
    const float* Wh = (const float*)d_in[3];
    const float* bh = (const float*)d_in[4];
    const float* Wl = (const float*)d_in[5];
    const float* bl = (const float*)d_in[6];
    float* out = (float*)d_out;

    char* p = (char*)d_ws;
    auto alloc = [&](size_t bytes) {
        char* r = p;
        p += (bytes + 255) & ~(size_t)255;
        return r;
    };
    u16*   WhTh = (u16*)alloc((size_t)16384 * 1024 * 2);
    u16*   WhTl = (u16*)alloc((size_t)16384 * 1024 * 2);
    u16*   WlTh = (u16*)alloc((size_t)1024 * 1024 * 2);
    u16*   WlTl = (u16*)alloc((size_t)1024 * 1024 * 2);
    float* WiP  = (float*)alloc((size_t)1024 * 16384 * 4);
    float* c4   = (float*)alloc((size_t)256 * 1024 * 4 * 4);
    u16*   h0h  = (u16*)alloc((size_t)262144 * 2);
    u16*   h0l  = (u16*)alloc((size_t)262144 * 2);
    u16*   h1h  = (u16*)alloc((size_t)262144 * 2);
    u16*   h1l  = (u16*)alloc((size_t)262144 * 2);
    float* bsum  = (float*)alloc((size_t)16384 * 4);
    float* bsumP = (float*)alloc((size_t)16384 * 4);
    int*   XT    = (int*)alloc((size_t)128 * 256 * 4);

    transpose_split<true><<<dim3(256, 16), 256, 0, stream>>>(Wh, WhTh, WhTl, 16384);
    transpose_split<false><<<dim3(16, 16), 256, 0, stream>>>(Wl, WlTh, WlTl, 1024);
    permute_wi<<<dim3(4, 1024), 256, 0, stream>>>(Wi, WiP);
    init_state<<<64, 256, 0, stream>>>(bsum, bsumP, bi, bh);
    transpose_x<<<128, 256, 0, stream>>>(X, XT);

    // Step 0 (h=0, c=0): writes h buffer 1
    cell0<<<1024, 256, 0, stream>>>(bsum, X, Wi, c4, h1h, h1l);

    for (int t = 1; t < 128; ++t) {
        const u16* ih = (t & 1) ? h1h : h0h;
        const u16* il = (t & 1) ? h1l : h0l;
        u16* oh = (t & 1) ? h0h : h1h;
        u16* ol = (t & 1) ? h0l : h1l;
        fused_step<<<256, 512, 0, stream>>>(ih, il, WhTh, WhTl, bsumP, WiP, XT, t, c4, oh, ol);
    }

    // t=127 wrote buffer 0
    gemm_logits<<<16, 256, 0, stream>>>(h0h, h0l, WlTh, WlTl, out, bl);
    logsoftmax_k<<<256, 256, 0, stream>>>(out);
}